// Round 22
// baseline (27.813 us; speedup 1.0000x reference)
//
#include <hip/hip_runtime.h>

#define HH 64
#define WW 64
#define TT 16
#define NPIX (HH * WW * TT)   // 65536
#define HALO_H 8              // tile 2 + 2*3
#define HALO_W 10             // tile 4 + 2*3
#define HWPOS (HALO_H * HALO_W)   // 80 halo (h,w) positions
#define CH_SZ (HWPOS * TT)    // 1280 floats per channel
#define NCH 12                // gui(9, prescaled) + est(3); var+img global

// lane i <- lane i-1 within 16-lane DPP rows (row_shr:1), 0-fill at row start.
__device__ __forceinline__ float dpp_up1(float x) {
    return __int_as_float(__builtin_amdgcn_update_dpp(
        0, __float_as_int(x), 0x111, 0xF, 0xF, true));
}
// lane i <- lane i+1 within 16-lane DPP rows (row_shl:1), 0-fill at row end.
__device__ __forceinline__ float dpp_dn1(float x) {
    return __int_as_float(__builtin_amdgcn_update_dpp(
        0, __float_as_int(x), 0x101, 0xF, 0xF, true));
}

// Champion body at 2 blocks/CU: the champion's occupancy limiter was LDS
// (96 KB -> 1 block/CU), NOT registers (VGPR=32 allows 8 waves/SIMD).
// Shrink LDS to 61.4 KB (stage gui+est only; var joins img on the global
// path) and launch 512 blocks of tile 2x4x16 -> 2 co-resident blocks/CU
// = 32 waves/CU = 8 waves/SIMD, doubling latency-hiding for the same
// K=2 + DPP body. launch_bounds(1024,4) is the empirically-clean variant
// (the ~200MB-scratch rounds all used (1024,8)). f32 everywhere; var/img
// per-XCD L2 footprint ~2.5MB < 4MiB (R6 proved no thrash at this
// residency). 16 column-splits: wave s does columns r = s + 16i < 49.
__global__ __launch_bounds__(1024, 4) void statdenoise_kernel(
    const float* __restrict__ img,
    const float* __restrict__ gui,
    const float* __restrict__ est,
    const float* __restrict__ var,
    float* __restrict__ out)
{
    __shared__ float smem[NCH * CH_SZ];   // 61.44 KB; aliased by reduction later

    const float SQS[9] = {0.31622776601683794f, 0.31622776601683794f, 0.31622776601683794f,
                          7.0710678118654755f,  7.0710678118654755f,  7.0710678118654755f,
                          3.1622776601683795f,  3.1622776601683795f,  3.1622776601683795f};
    const float G2 = 2.907f * 2.907f;   // gamma^2

    const int tid  = threadIdx.x;
    const int lane = tid & 63;
    const int s    = tid >> 6;      // wave id == column-split 0..15
    const int tg   = lane & 7;      // t-group 0..7
    const int hwl  = lane >> 3;     // tile pixel 0..7 (2h x 4w)
    const int t0   = tg * 2;        // owns t0, t0+1
    const int h0   = (blockIdx.x >> 4) << 1;   // 32 h-tiles x 2 rows
    const int w0   = (blockIdx.x & 15) << 2;   // 16 w-tiles x 4 cols

    // ---- stage gui (prescaled) + est for the 8x10x16 halo (edge-clamped;
    //      OOB pairs masked later by inb, same semantics as clamped loads) ----
#pragma unroll
    for (int rep = 0; rep < 2; ++rep) {
        const int q = tid + rep * 1024;
        if (q < CH_SZ) {
            const int t   = q & 15;
            const int hwq = q >> 4;                  // 0..79
            const int hq  = (hwq * 205) >> 11;       // exact /10 for hwq<1024
            const int wq  = hwq - hq * 10;
            const int hs  = min(max(h0 - 3 + hq, 0), HH - 1);
            const int ws  = min(max(w0 - 3 + wq, 0), WW - 1);
            const int g   = (((hs << 6) + ws) << 4) + t;
#pragma unroll
            for (int c = 0; c < 9; ++c)
                smem[c * CH_SZ + q] = gui[c * NPIX + g] * SQS[c];   // prescaled
#pragma unroll
            for (int c = 0; c < 3; ++c)
                smem[(9 + c) * CH_SZ + q] = est[c * NPIX + g];
        }
    }
    __syncthreads();

    const int th = hwl >> 2, tw = hwl & 3;     // tile-local pixel (2h x 4w)
    const int hg = h0 + th,  wg = w0 + tw;     // global pixel
    const int cpix = ((hg << 6) + wg) * 16 + t0;

    // center values: gui/est from LDS, var from global (column-invariant)
    const int rowc = (th + 3) * 10 + (tw + 3);
    const int lc = rowc * 16 + t0;
    float2 gc[9];
#pragma unroll
    for (int c = 0; c < 9; ++c) gc[c] = *(const float2*)&smem[c * CH_SZ + lc];
    float2 ec[3], vc[3];
#pragma unroll
    for (int c = 0; c < 3; ++c) {
        ec[c] = *(const float2*)&smem[(9 + c) * CH_SZ + lc];
        vc[c] = *(const float2*)&var[c * NPIX + cpix];
    }

    const bool vLo = (t0 != 0);    // dt=-1 valid; also masks DPP boundary garbage
    const bool vHi = (t0 != 14);   // dt=+1 valid; also masks DPP boundary garbage

    float acc[2][4] = {};   // per owned t: {r,g,b,wsum}

    int dh = s / 7 - 3, dw = s % 7 - 3;   // column r = s, then += 16
    for (int r = s; r < 49; r += 16) {
        // halo coords always in range: th+dh+3 in [0,7], tw+dw+3 in [0,9]
        const int lb  = ((th + dh + 3) * 10 + (tw + dw + 3)) * 16 + t0;
        const bool inb = ((unsigned)(hg + dh) < (unsigned)HH) &
                         ((unsigned)(wg + dw) < (unsigned)WW);
        // clamped global offset for var/img
        const int hhc = min(max(hg + dh, 0), HH - 1);
        const int wwc = min(max(wg + dw, 0), WW - 1);
        const int gnb = (((hhc << 6) + wwc) << 4) + t0;

        // ---- bilateral over 9 prescaled guidance channels, 6 pairs ----
        float sb[2][3] = {};
#pragma unroll
        for (int c = 0; c < 9; ++c) {
            float2 m = *(const float2*)&smem[c * CH_SZ + lb];
            float nv[4] = {dpp_up1(m.y), m.x, m.y, dpp_dn1(m.x)};   // t0-1..t0+2
#pragma unroll
            for (int e = 0; e < 2; ++e) {
                float ce = e ? gc[c].y : gc[c].x;
#pragma unroll
                for (int k = 0; k < 3; ++k) {
                    float d = ce - nv[e + k];
                    sb[e][k] = fmaf(d, d, sb[e][k]);   // sig folded into inputs
                }
            }
        }

        // ---- membership (division-free Welch t-test, simplified) ----
        // mem = (d2==0) | (d2 < G2*V & vce!=0 & vnv!=0). Case-verified vs
        // reference; OOB h/w neighbors provably weight-0 -> masked by inb.
        bool mem[2][3] = {{true, true, true}, {true, true, true}};
#pragma unroll
        for (int c = 0; c < 3; ++c) {
            float2 em = *(const float2*)&smem[(9 + c) * CH_SZ + lb];
            float2 vm = *(const float2*)&var[c * NPIX + gnb];   // global path
            float env[4] = {dpp_up1(em.y), em.x, em.y, dpp_dn1(em.x)};
            float vnv[4] = {dpp_up1(vm.y), vm.x, vm.y, dpp_dn1(vm.x)};
#pragma unroll
            for (int e = 0; e < 2; ++e) {
                float ece = e ? ec[c].y : ec[c].x;
                float vce = e ? vc[c].y : vc[c].x;
#pragma unroll
                for (int k = 0; k < 3; ++k) {
                    float d  = ece - env[e + k];
                    float d2 = d * d;
                    float V  = vce + vnv[e + k];
                    bool ok = (d2 == 0.f) |
                              ((d2 < G2 * V) & !((vce == 0.f) | (vnv[e + k] == 0.f)));
                    mem[e][k] = mem[e][k] & ok;
                }
            }
        }

        // ---- weights ----
        float wt[2][3];
#pragma unroll
        for (int e = 0; e < 2; ++e) {
#pragma unroll
            for (int k = 0; k < 3; ++k) {
                bool ok = inb && mem[e][k];
                if (e == 0 && k == 0) ok = ok && vLo;   // tt = t0-1
                if (e == 1 && k == 2) ok = ok && vHi;   // tt = t0+2
                wt[e][k] = ok ? __expf(-0.5f * sb[e][k]) : 0.f;
            }
        }

        // ---- accumulate image (global path; consumed last, latency hidden) ----
#pragma unroll
        for (int c = 0; c < 3; ++c) {
            float2 im = *(const float2*)&img[c * NPIX + gnb];
            float iv[4] = {dpp_up1(im.y), im.x, im.y, dpp_dn1(im.x)};
#pragma unroll
            for (int e = 0; e < 2; ++e) {
                acc[e][c] = fmaf(wt[e][0], iv[e],
                            fmaf(wt[e][1], iv[e + 1],
                            fmaf(wt[e][2], iv[e + 2], acc[e][c])));
            }
        }
#pragma unroll
        for (int e = 0; e < 2; ++e)
            acc[e][3] += wt[e][0] + wt[e][1] + wt[e][2];

        dw += 16;
        while (dw > 3) { dw -= 7; ++dh; }
    }

    // ---- combine the 16 splits (alias staging LDS after all reads done) ----
    __syncthreads();
    float4* red = (float4*)smem;          // 16*64*2 float4 = 32 KB < 61.44 KB
    red[(s * 64 + lane) * 2 + 0] = make_float4(acc[0][0], acc[0][1], acc[0][2], acc[0][3]);
    red[(s * 64 + lane) * 2 + 1] = make_float4(acc[1][0], acc[1][1], acc[1][2], acc[1][3]);
    __syncthreads();

    if (tid < 128) {
        const int hw_ = tid >> 4;           // tile pixel 0..7
        const int t_  = tid & 15;           // t 0..15
        const int tg_ = t_ >> 1, e_ = t_ & 1;
        const int li  = hw_ * 8 + tg_;      // lane that owns this (hw, t0) group
        float4 sum = make_float4(0.f, 0.f, 0.f, 0.f);
#pragma unroll
        for (int q = 0; q < 16; ++q) {
            float4 v = red[(q * 64 + li) * 2 + e_];
            sum.x += v.x; sum.y += v.y; sum.z += v.z; sum.w += v.w;
        }
        const int th_ = hw_ >> 2, tw_ = hw_ & 3;
        const int px = ((((h0 + th_) << 6) + (w0 + tw_)) << 4) + t_;
        const float inv = 1.f / sum.w;      // wsum >= 1 (center weight == 1)
        out[0 * NPIX + px] = sum.x * inv;
        out[1 * NPIX + px] = sum.y * inv;
        out[2 * NPIX + px] = sum.z * inv;
    }
}

extern "C" void kernel_launch(void* const* d_in, const int* in_sizes, int n_in,
                              void* d_out, int out_size, void* d_ws, size_t ws_size,
                              hipStream_t stream) {
    const float* img = (const float*)d_in[0];
    const float* gui = (const float*)d_in[1];
    const float* est = (const float*)d_in[2];
    const float* var = (const float*)d_in[3];
    float* out = (float*)d_out;

    dim3 grid(512);     // 32x16 tiles of 2x4x16; 2 blocks/CU (LDS 61.4 KB)
    dim3 block(1024);   // 16 waves = 16 column-splits
    statdenoise_kernel<<<grid, block, 0, stream>>>(img, gui, est, var, out);
}

// Round 23
// 27.742 us; speedup vs baseline: 1.0025x; 1.0025x over previous
//
#include <hip/hip_runtime.h>

#define HH 64
#define WW 64
#define TT 16
#define NPIX (HH * WW * TT)   // 65536
#define HALO_H 8              // tile 2 + 2*3
#define HALO_W 10             // tile 4 + 2*3
#define HWPOS (HALO_H * HALO_W)   // 80 halo (h,w) positions
#define CH_SZ (HWPOS * TT)    // 1280 floats per channel
#define NCH 15                // gui(9, prescaled) + est(3) + var(3); img global

// lane i <- lane i-1 within 16-lane DPP rows (row_shr:1), 0-fill at row start.
__device__ __forceinline__ float dpp_up1(float x) {
    return __int_as_float(__builtin_amdgcn_update_dpp(
        0, __float_as_int(x), 0x111, 0xF, 0xF, true));
}
// lane i <- lane i+1 within 16-lane DPP rows (row_shl:1), 0-fill at row end.
__device__ __forceinline__ float dpp_dn1(float x) {
    return __int_as_float(__builtin_amdgcn_update_dpp(
        0, __float_as_int(x), 0x101, 0xF, 0xF, true));
}

// The clean occupancy test: champion body (all 15 K-loop channels in LDS,
// img global at chain tail, K=2 + DPP, prescaled gui, simplified
// membership) at tile 2x4x16 / halo 8x10x16 -> 76.8 KB LDS -> 2 blocks/CU
// co-reside = 32 waves/CU = 8 waves/SIMD (vs champion's 4). This is R10's
// geometry with launch_bounds(1024,4): every ~200MB-scratch round used
// (1024,8) [R8/10/15/19]; every clean 1024-thread round used (1024,4).
// R22 (27.8us) confounded occupancy with var-on-global (6 mid-chain
// ~200cy loads/col); here the only delta vs the 25.3us champion is waves.
// 16 column-splits: wave s does columns r = s + 16i < 49.
__global__ __launch_bounds__(1024, 4) void statdenoise_kernel(
    const float* __restrict__ img,
    const float* __restrict__ gui,
    const float* __restrict__ est,
    const float* __restrict__ var,
    float* __restrict__ out)
{
    __shared__ float smem[NCH * CH_SZ];   // 76.8 KB; aliased by reduction later

    const float SQS[9] = {0.31622776601683794f, 0.31622776601683794f, 0.31622776601683794f,
                          7.0710678118654755f,  7.0710678118654755f,  7.0710678118654755f,
                          3.1622776601683795f,  3.1622776601683795f,  3.1622776601683795f};
    const float G2 = 2.907f * 2.907f;   // gamma^2

    const int tid  = threadIdx.x;
    const int lane = tid & 63;
    const int s    = tid >> 6;      // wave id == column-split 0..15
    const int tg   = lane & 7;      // t-group 0..7
    const int hwl  = lane >> 3;     // tile pixel 0..7 (2h x 4w)
    const int t0   = tg * 2;        // owns t0, t0+1
    const int h0   = (blockIdx.x >> 4) << 1;   // 32 h-tiles x 2 rows
    const int w0   = (blockIdx.x & 15) << 2;   // 16 w-tiles x 4 cols

    // ---- stage 15 channels of the 8x10x16 halo (edge-clamped; OOB pairs
    //      masked later by inb, same semantics as the clamped loads) ----
#pragma unroll
    for (int rep = 0; rep < 2; ++rep) {
        const int q = tid + rep * 1024;
        if (q < CH_SZ) {
            const int t   = q & 15;
            const int hwq = q >> 4;                  // 0..79
            const int hq  = (hwq * 205) >> 11;       // exact /10 for hwq<1024
            const int wq  = hwq - hq * 10;
            const int hs  = min(max(h0 - 3 + hq, 0), HH - 1);
            const int ws  = min(max(w0 - 3 + wq, 0), WW - 1);
            const int g   = (((hs << 6) + ws) << 4) + t;
#pragma unroll
            for (int c = 0; c < 9; ++c)
                smem[c * CH_SZ + q] = gui[c * NPIX + g] * SQS[c];   // prescaled
#pragma unroll
            for (int c = 0; c < 3; ++c) {
                smem[(9 + c)  * CH_SZ + q] = est[c * NPIX + g];
                smem[(12 + c) * CH_SZ + q] = var[c * NPIX + g];
            }
        }
    }
    __syncthreads();

    const int th = hwl >> 2, tw = hwl & 3;     // tile-local pixel (2h x 4w)
    const int hg = h0 + th,  wg = w0 + tw;     // global pixel

    // center values from LDS (center is inside the halo)
    const int rowc = (th + 3) * 10 + (tw + 3);
    const int lc = rowc * 16 + t0;
    float2 gc[9];
#pragma unroll
    for (int c = 0; c < 9; ++c) gc[c] = *(const float2*)&smem[c * CH_SZ + lc];
    float2 ec[3], vc[3];
#pragma unroll
    for (int c = 0; c < 3; ++c) {
        ec[c] = *(const float2*)&smem[(9 + c)  * CH_SZ + lc];
        vc[c] = *(const float2*)&smem[(12 + c) * CH_SZ + lc];
    }

    const bool vLo = (t0 != 0);    // dt=-1 valid; also masks DPP boundary garbage
    const bool vHi = (t0 != 14);   // dt=+1 valid; also masks DPP boundary garbage

    float acc[2][4] = {};   // per owned t: {r,g,b,wsum}

    int dh = s / 7 - 3, dw = s % 7 - 3;   // column r = s, then += 16
    for (int r = s; r < 49; r += 16) {
        // halo coords always in range: th+dh+3 in [0,7], tw+dw+3 in [0,9]
        const int lb  = ((th + dh + 3) * 10 + (tw + dw + 3)) * 16 + t0;
        const bool inb = ((unsigned)(hg + dh) < (unsigned)HH) &
                         ((unsigned)(wg + dw) < (unsigned)WW);
        // clamped global offset for img
        const int hhc = min(max(hg + dh, 0), HH - 1);
        const int wwc = min(max(wg + dw, 0), WW - 1);
        const int gnb = (((hhc << 6) + wwc) << 4) + t0;

        // ---- bilateral over 9 prescaled guidance channels, 6 pairs ----
        float sb[2][3] = {};
#pragma unroll
        for (int c = 0; c < 9; ++c) {
            float2 m = *(const float2*)&smem[c * CH_SZ + lb];
            float nv[4] = {dpp_up1(m.y), m.x, m.y, dpp_dn1(m.x)};   // t0-1..t0+2
#pragma unroll
            for (int e = 0; e < 2; ++e) {
                float ce = e ? gc[c].y : gc[c].x;
#pragma unroll
                for (int k = 0; k < 3; ++k) {
                    float d = ce - nv[e + k];
                    sb[e][k] = fmaf(d, d, sb[e][k]);   // sig folded into inputs
                }
            }
        }

        // ---- membership (division-free Welch t-test, simplified) ----
        // mem = (d2==0) | (d2 < G2*V & vce!=0 & vnv!=0). Case-verified vs
        // reference; OOB h/w neighbors provably weight-0 -> masked by inb.
        bool mem[2][3] = {{true, true, true}, {true, true, true}};
#pragma unroll
        for (int c = 0; c < 3; ++c) {
            float2 em = *(const float2*)&smem[(9 + c)  * CH_SZ + lb];
            float2 vm = *(const float2*)&smem[(12 + c) * CH_SZ + lb];
            float env[4] = {dpp_up1(em.y), em.x, em.y, dpp_dn1(em.x)};
            float vnv[4] = {dpp_up1(vm.y), vm.x, vm.y, dpp_dn1(vm.x)};
#pragma unroll
            for (int e = 0; e < 2; ++e) {
                float ece = e ? ec[c].y : ec[c].x;
                float vce = e ? vc[c].y : vc[c].x;
#pragma unroll
                for (int k = 0; k < 3; ++k) {
                    float d  = ece - env[e + k];
                    float d2 = d * d;
                    float V  = vce + vnv[e + k];
                    bool ok = (d2 == 0.f) |
                              ((d2 < G2 * V) & !((vce == 0.f) | (vnv[e + k] == 0.f)));
                    mem[e][k] = mem[e][k] & ok;
                }
            }
        }

        // ---- weights ----
        float wt[2][3];
#pragma unroll
        for (int e = 0; e < 2; ++e) {
#pragma unroll
            for (int k = 0; k < 3; ++k) {
                bool ok = inb && mem[e][k];
                if (e == 0 && k == 0) ok = ok && vLo;   // tt = t0-1
                if (e == 1 && k == 2) ok = ok && vHi;   // tt = t0+2
                wt[e][k] = ok ? __expf(-0.5f * sb[e][k]) : 0.f;
            }
        }

        // ---- accumulate image (global path; consumed last, latency hidden) ----
#pragma unroll
        for (int c = 0; c < 3; ++c) {
            float2 im = *(const float2*)&img[c * NPIX + gnb];
            float iv[4] = {dpp_up1(im.y), im.x, im.y, dpp_dn1(im.x)};
#pragma unroll
            for (int e = 0; e < 2; ++e) {
                acc[e][c] = fmaf(wt[e][0], iv[e],
                            fmaf(wt[e][1], iv[e + 1],
                            fmaf(wt[e][2], iv[e + 2], acc[e][c])));
            }
        }
#pragma unroll
        for (int e = 0; e < 2; ++e)
            acc[e][3] += wt[e][0] + wt[e][1] + wt[e][2];

        dw += 16;
        while (dw > 3) { dw -= 7; ++dh; }
    }

    // ---- combine the 16 splits (alias staging LDS after all reads done) ----
    __syncthreads();
    float4* red = (float4*)smem;          // 16*64*2 float4 = 32 KB < 76.8 KB
    red[(s * 64 + lane) * 2 + 0] = make_float4(acc[0][0], acc[0][1], acc[0][2], acc[0][3]);
    red[(s * 64 + lane) * 2 + 1] = make_float4(acc[1][0], acc[1][1], acc[1][2], acc[1][3]);
    __syncthreads();

    if (tid < 128) {
        const int hw_ = tid >> 4;           // tile pixel 0..7
        const int t_  = tid & 15;           // t 0..15
        const int tg_ = t_ >> 1, e_ = t_ & 1;
        const int li  = hw_ * 8 + tg_;      // lane that owns this (hw, t0) group
        float4 sum = make_float4(0.f, 0.f, 0.f, 0.f);
#pragma unroll
        for (int q = 0; q < 16; ++q) {
            float4 v = red[(q * 64 + li) * 2 + e_];
            sum.x += v.x; sum.y += v.y; sum.z += v.z; sum.w += v.w;
        }
        const int th_ = hw_ >> 2, tw_ = hw_ & 3;
        const int px = ((((h0 + th_) << 6) + (w0 + tw_)) << 4) + t_;
        const float inv = 1.f / sum.w;      // wsum >= 1 (center weight == 1)
        out[0 * NPIX + px] = sum.x * inv;
        out[1 * NPIX + px] = sum.y * inv;
        out[2 * NPIX + px] = sum.z * inv;
    }
}

extern "C" void kernel_launch(void* const* d_in, const int* in_sizes, int n_in,
                              void* d_out, int out_size, void* d_ws, size_t ws_size,
                              hipStream_t stream) {
    const float* img = (const float*)d_in[0];
    const float* gui = (const float*)d_in[1];
    const float* est = (const float*)d_in[2];
    const float* var = (const float*)d_in[3];
    float* out = (float*)d_out;

    dim3 grid(512);     // 32x16 tiles of 2x4x16; 2 blocks/CU (LDS 76.8 KB)
    dim3 block(1024);   // 16 waves = 16 column-splits
    statdenoise_kernel<<<grid, block, 0, stream>>>(img, gui, est, var, out);
}